// Round 3
// baseline (1162.468 us; speedup 1.0000x reference)
//
#include <hip/hip_runtime.h>

// Problem constants: Q,K,V (4,8,1024,64) f32.
#define SCALE 0.125f

// ws layout (float offsets)
//  FQ:   0          (2097152)   FK: 2097152
//  CN:   4194304  SN: 4456448  CM: 4718592  SM: 5767168
//  T:    6815744    (4 x 2097152 = 8388608)  [dead after stage2]
//  Qp:   6815744 (overlays T)   Kp: 15204352
#define WS_FLOATS_NEEDED 23592960ull

// ---------------------------------------------------------------- trig tables
__global__ void gen_mats(float* __restrict__ CN, float* __restrict__ SN,
                         float* __restrict__ CM, float* __restrict__ SM) {
    int idx = blockIdx.x * 256 + threadIdx.x;
    const float twopi = 6.28318530717958647692f;
    if (idx < 512 * 512) {
        int a = idx >> 9, b = idx & 511;
        int t = (a * b) & 511;
        float s, c;
        sincosf(twopi * (float)t * (1.0f / 512.0f), &s, &c);
        CN[idx] = c; SN[idx] = s;
    }
    int idx2 = idx - 512 * 512;
    if (idx2 >= 0 && idx2 < 1024 * 1024) {
        int a = idx2 >> 10, b = idx2 & 1023;
        int t = (a * b) & 1023;
        float s, c;
        sincosf(twopi * (float)t * (1.0f / 1024.0f), &s, &c);
        CM[idx2] = c; SM[idx2] = s;
    }
}

// ---------------- stage1: Tc += X*CN, Ts += X*SN, cols 0..319, K-split x2
__global__ __launch_bounds__(256) void stage1_fused(
        const float* __restrict__ Qg, const float* __restrict__ Kg,
        const float* __restrict__ CN, const float* __restrict__ SN,
        float* __restrict__ TcQ, float* __restrict__ TsQ,
        float* __restrict__ TcK, float* __restrict__ TsK) {
    int inp = blockIdx.z >> 1, kh = blockIdx.z & 1;
    const float* X = inp ? Kg : Qg;
    float* Tc = inp ? TcK : TcQ;
    float* Ts = inp ? TsK : TsQ;
    __shared__ float At[16][68];                  // [kk][m]
    __shared__ float Bc[16][68], Bs[16][68];      // [kk][n]
    int m0 = blockIdx.y * 64, n0 = blockIdx.x * 64;
    int tn = threadIdx.x & 15, tm = threadIdx.x >> 4;
    int mA = threadIdx.x >> 2, kqA = threadIdx.x & 3;
    int colB = threadIdx.x & 63, rowB = threadIdx.x >> 6;
    float accC[4][4] = {}, accS[4][4] = {};
    int kbeg = kh * 256;
    for (int k0 = kbeg; k0 < kbeg + 256; k0 += 16) {
        float4 va = *(const float4*)&X[(size_t)(m0 + mA) * 512 + k0 + 4 * kqA];
        At[4 * kqA + 0][mA] = va.x; At[4 * kqA + 1][mA] = va.y;
        At[4 * kqA + 2][mA] = va.z; At[4 * kqA + 3][mA] = va.w;
#pragma unroll
        for (int r = 0; r < 4; r++) {
            Bc[rowB + 4 * r][colB] = CN[(size_t)(k0 + rowB + 4 * r) * 512 + n0 + colB];
            Bs[rowB + 4 * r][colB] = SN[(size_t)(k0 + rowB + 4 * r) * 512 + n0 + colB];
        }
        __syncthreads();
#pragma unroll
        for (int kk = 0; kk < 16; kk++) {
            float4 a  = *(const float4*)&At[kk][tm * 4];
            float4 bc = *(const float4*)&Bc[kk][tn * 4];
            float4 bs = *(const float4*)&Bs[kk][tn * 4];
            float av[4]  = {a.x, a.y, a.z, a.w};
            float bcv[4] = {bc.x, bc.y, bc.z, bc.w};
            float bsv[4] = {bs.x, bs.y, bs.z, bs.w};
#pragma unroll
            for (int i = 0; i < 4; i++)
#pragma unroll
                for (int j = 0; j < 4; j++) {
                    accC[i][j] += av[i] * bcv[j];
                    accS[i][j] += av[i] * bsv[j];
                }
        }
        __syncthreads();
    }
#pragma unroll
    for (int i = 0; i < 4; i++) {
        size_t rbase = (size_t)(m0 + tm * 4 + i) * 512 + n0 + tn * 4;
#pragma unroll
        for (int j = 0; j < 4; j++) {
            atomicAdd(&Tc[rbase + j], accC[i][j]);
            atomicAdd(&Ts[rbase + j], accS[i][j]);
        }
    }
}

// ---------------- stage2: F += CM*Tc - SM*Ts, cols 0..319, K-split x4
__global__ __launch_bounds__(256) void stage2_fused(
        const float* __restrict__ CM, const float* __restrict__ SM,
        const float* __restrict__ TcQ, const float* __restrict__ TsQ,
        const float* __restrict__ TcK, const float* __restrict__ TsK,
        float* __restrict__ FQ, float* __restrict__ FK) {
    int z = blockIdx.z;
    int split = z >> 3, zb = z & 7, inp = zb >> 2, b = zb & 3;
    const float* Tc = (inp ? TcK : TcQ) + (size_t)b * 524288;
    const float* Ts = (inp ? TsK : TsQ) + (size_t)b * 524288;
    float* F = (inp ? FK : FQ) + (size_t)b * 524288;
    __shared__ float Ac[16][68], Asn[16][68];     // [kk][m]
    __shared__ float Bc[16][68], Bs[16][68];      // [kk][n]
    int m0 = blockIdx.y * 64, n0 = blockIdx.x * 64;
    int tn = threadIdx.x & 15, tm = threadIdx.x >> 4;
    int mA = threadIdx.x >> 2, kqA = threadIdx.x & 3;
    int colB = threadIdx.x & 63, rowB = threadIdx.x >> 6;
    float acc[4][4] = {};
    int kbeg = split * 256;
    for (int k0 = kbeg; k0 < kbeg + 256; k0 += 16) {
        float4 vc = *(const float4*)&CM[(size_t)(m0 + mA) * 1024 + k0 + 4 * kqA];
        float4 vs = *(const float4*)&SM[(size_t)(m0 + mA) * 1024 + k0 + 4 * kqA];
        Ac [4 * kqA + 0][mA] = vc.x; Ac [4 * kqA + 1][mA] = vc.y;
        Ac [4 * kqA + 2][mA] = vc.z; Ac [4 * kqA + 3][mA] = vc.w;
        Asn[4 * kqA + 0][mA] = vs.x; Asn[4 * kqA + 1][mA] = vs.y;
        Asn[4 * kqA + 2][mA] = vs.z; Asn[4 * kqA + 3][mA] = vs.w;
#pragma unroll
        for (int r = 0; r < 4; r++) {
            Bc[rowB + 4 * r][colB] = Tc[(size_t)(k0 + rowB + 4 * r) * 512 + n0 + colB];
            Bs[rowB + 4 * r][colB] = Ts[(size_t)(k0 + rowB + 4 * r) * 512 + n0 + colB];
        }
        __syncthreads();
#pragma unroll
        for (int kk = 0; kk < 16; kk++) {
            float4 ac = *(const float4*)&Ac[kk][tm * 4];
            float4 as = *(const float4*)&Asn[kk][tm * 4];
            float4 bc = *(const float4*)&Bc[kk][tn * 4];
            float4 bs = *(const float4*)&Bs[kk][tn * 4];
            float acv[4] = {ac.x, ac.y, ac.z, ac.w};
            float asv[4] = {as.x, as.y, as.z, as.w};
            float bcv[4] = {bc.x, bc.y, bc.z, bc.w};
            float bsv[4] = {bs.x, bs.y, bs.z, bs.w};
#pragma unroll
            for (int i = 0; i < 4; i++)
#pragma unroll
                for (int j = 0; j < 4; j++)
                    acc[i][j] += acv[i] * bcv[j] - asv[i] * bsv[j];
        }
        __syncthreads();
    }
#pragma unroll
    for (int i = 0; i < 4; i++) {
        size_t rbase = (size_t)(m0 + tm * 4 + i) * 512 + n0 + tn * 4;
#pragma unroll
        for (int j = 0; j < 4; j++)
            atomicAdd(&F[rbase + j], acc[i][j]);
    }
}

// ------------- mirror: F[m, n] = F[(1024-m)%1024, 512-n]  for n in 257..511
__global__ void mirror_f(float* __restrict__ FQ, float* __restrict__ FK) {
    int z = blockIdx.x >> 10;
    int m = blockIdx.x & 1023;
    float* F = (z >= 4) ? (FK + (size_t)(z - 4) * 524288) : (FQ + (size_t)z * 524288);
    int t = threadIdx.x;
    if (t < 255) {
        int n = 257 + t;
        F[(size_t)m * 512 + n] = F[(size_t)((1024 - m) & 1023) * 512 + (512 - n)];
    }
}

// ------------------------------------ multi-scale conv gather (all 4 scales)
template <int C>
__device__ inline float conv_gather(const float* __restrict__ Fb, int rb, int cb, int d,
                                    const float* __restrict__ w) {
    float acc = 0.f;
#pragma unroll
    for (int ci = 0; ci < C; ci++) {
        int u = ci * 64 + d;
        int q = u / C, r = u - q * C;
        int row = rb + r - C;
        int col = cb + q - C;
        if (row >= 0 && col >= 0)
            acc += w[ci] * Fb[(row << 9) + col];
    }
    return acc;
}

__global__ __launch_bounds__(256) void conv_all(const float* __restrict__ F,
        float* __restrict__ out,
        const float* __restrict__ w1, const float* __restrict__ bb1,
        const float* __restrict__ w3, const float* __restrict__ bb3,
        const float* __restrict__ w6, const float* __restrict__ bb6,
        const float* __restrict__ w9, const float* __restrict__ bb9,
        float scale) {
    int idx = blockIdx.x * 256 + threadIdx.x;
    int d = idx & 63;
    int l = (idx >> 6) & 1023;
    int h = (idx >> 16) & 7;
    int b = idx >> 19;
    int g = (h << 10) + l;
    int rb = g >> 3;
    int cb = (g & 7) << 6;
    const float* Fb = F + (size_t)b * (1024 * 512);
    size_t ob = (size_t)((b * 8 + h) * 4) * 65536 + l * 64 + d;
    out[ob]             = (conv_gather<1>(Fb, rb, cb, d, w1) + bb1[0]) * scale;
    out[ob + 65536]     = (conv_gather<3>(Fb, rb, cb, d, w3) + bb3[0]) * scale;
    out[ob + 2 * 65536] = (conv_gather<6>(Fb, rb, cb, d, w6) + bb6[0]) * scale;
    out[ob + 3 * 65536] = (conv_gather<9>(Fb, rb, cb, d, w9) + bb9[0]) * scale;
}

// ------------- fused scores (4 GEMMs K=64) + softmax over p + q-reduction
// LDS k-major with XOR swizzle: phys_col = col ^ (((kk>>3)&3)<<2)  (2-way max)
__global__ __launch_bounds__(256) void scores_attn(const float* __restrict__ Qp,
                                                   const float* __restrict__ Kp,
                                                   float* __restrict__ attn_out) {
    int bh = blockIdx.z;
    int k0 = blockIdx.x * 64, q0 = blockIdx.y * 64;
    __shared__ float Aq[64][68];   // [kk][q]
    __shared__ float Bk[64][68];   // [kk][k]
    int tn = threadIdx.x & 15, tm = threadIdx.x >> 4;
    float acc[4][4][4];   // [p][i(q)][j(k)]
#pragma unroll
    for (int p = 0; p < 4; p++)
#pragma unroll
        for (int i = 0; i < 4; i++)
#pragma unroll
            for (int j = 0; j < 4; j++) acc[p][i][j] = 0.f;

    for (int p = 0; p < 4; p++) {
        const float* Ab = Qp + (size_t)(bh * 4 + p) * 65536 + (size_t)q0 * 64;
        const float* Bb = Kp + (size_t)(bh * 4 + p) * 65536 + (size_t)k0 * 64;
        __syncthreads();
#pragma unroll
        for (int r = 0; r < 4; r++) {
            int rl = tm + 16 * r;               // local q (for A) / k (for B)
            float4 va = *(const float4*)&Ab[(size_t)rl * 64 + 4 * tn];
            float4 vb = *(const float4*)&Bb[(size_t)rl * 64 + 4 * tn];
            float av[4] = {va.x, va.y, va.z, va.w};
            float bv[4] = {vb.x, vb.y, vb.z, vb.w};
#pragma unroll
            for (int x = 0; x < 4; x++) {
                int kk = 4 * tn + x;
                int sw = ((kk >> 3) & 3) << 2;
                Aq[kk][rl ^ sw] = av[x];
                Bk[kk][rl ^ sw] = bv[x];
            }
        }
        __syncthreads();
#pragma unroll
        for (int kk = 0; kk < 64; kk++) {
            int sw = ((kk >> 3) & 3) << 2;
            float4 a = *(const float4*)&Aq[kk][(tm * 4) ^ sw];
            float4 b = *(const float4*)&Bk[kk][(tn * 4) ^ sw];
            float av[4] = {a.x, a.y, a.z, a.w};
            float bv[4] = {b.x, b.y, b.z, b.w};
#pragma unroll
            for (int i = 0; i < 4; i++)
#pragma unroll
                for (int j = 0; j < 4; j++) acc[p][i][j] += av[i] * bv[j];
        }
    }

    // softmax over p per (q,k); accumulate over this thread's 4 q's
    // (SCALE already folded into Qp by conv_all)
    float qsum[4][4];     // [p][j]
#pragma unroll
    for (int p = 0; p < 4; p++)
#pragma unroll
        for (int j = 0; j < 4; j++) qsum[p][j] = 0.f;
#pragma unroll
    for (int i = 0; i < 4; i++)
#pragma unroll
        for (int j = 0; j < 4; j++) {
            float s0 = acc[0][i][j], s1 = acc[1][i][j];
            float s2 = acc[2][i][j], s3 = acc[3][i][j];
            float m = fmaxf(fmaxf(s0, s1), fmaxf(s2, s3));
            float e0 = expf(s0 - m), e1 = expf(s1 - m);
            float e2 = expf(s2 - m), e3 = expf(s3 - m);
            float inv = 1.0f / (e0 + e1 + e2 + e3);
            qsum[0][j] += e0 * inv; qsum[1][j] += e1 * inv;
            qsum[2][j] += e2 * inv; qsum[3][j] += e3 * inv;
        }

    __syncthreads();       // inner-loop LDS reads done before red overwrite
    float* red = &Aq[0][0];   // 4096 floats needed, 4352 available
#pragma unroll
    for (int p = 0; p < 4; p++)
#pragma unroll
        for (int j = 0; j < 4; j++)
            red[(p * 64 + tn * 4 + j) * 16 + tm] = qsum[p][j];
    __syncthreads();
    int pp = threadIdx.x >> 6, kk = threadIdx.x & 63;
    float s = 0.f;
#pragma unroll
    for (int t = 0; t < 16; t++) s += red[(pp * 64 + kk) * 16 + t];
    atomicAdd(&attn_out[(size_t)(bh * 4 + pp) * 1024 + k0 + kk], s);
}

// ------------------------------- context[b,h,q,:] = colsum(V[b,h]) broadcast
__global__ __launch_bounds__(256) void context_kernel(const float* __restrict__ V,
                                                      float* __restrict__ out) {
    int bh = blockIdx.x;
    const float* Vb = V + (size_t)bh * 65536;
    __shared__ float part[4][64];
    __shared__ float colsum[64];
    int d = threadIdx.x & 63, grp = threadIdx.x >> 6;
    float s = 0.f;
    for (int r = grp; r < 1024; r += 4) s += Vb[r * 64 + d];
    part[grp][d] = s;
    __syncthreads();
    if (threadIdx.x < 64) colsum[d] = part[0][d] + part[1][d] + part[2][d] + part[3][d];
    __syncthreads();
    float val = colsum[d];
    float* ob = out + (size_t)bh * 65536;
    for (int q = grp; q < 1024; q += 4) ob[q * 64 + d] = val;
}

// ---------------------------------------------------------------------------
extern "C" void kernel_launch(void* const* d_in, const int* in_sizes, int n_in,
                              void* d_out, int out_size, void* d_ws, size_t ws_size,
                              hipStream_t stream) {
    if (n_in < 19) return;
    if ((size_t)ws_size < WS_FLOATS_NEEDED * sizeof(float)) return;
    const float* Q = (const float*)d_in[0];
    const float* K = (const float*)d_in[1];
    const float* V = (const float*)d_in[2];
    const float* wq[4] = {(const float*)d_in[3], (const float*)d_in[5],
                          (const float*)d_in[7], (const float*)d_in[9]};
    const float* bq[4] = {(const float*)d_in[4], (const float*)d_in[6],
                          (const float*)d_in[8], (const float*)d_in[10]};
    const float* wk[4] = {(const float*)d_in[11], (const float*)d_in[13],
                          (const float*)d_in[15], (const float*)d_in[17]};
    const float* bk[4] = {(const float*)d_in[12], (const float*)d_in[14],
                          (const float*)d_in[16], (const float*)d_in[18]};

    float* ws  = (float*)d_ws;
    float* FQ  = ws;
    float* FK  = ws + 2097152;
    float* CN  = ws + 4194304;
    float* SN  = ws + 4456448;
    float* CM  = ws + 4718592;
    float* SM  = ws + 5767168;
    float* TcQ = ws + 6815744;
    float* TsQ = TcQ + 2097152;
    float* TcK = TsQ + 2097152;
    float* TsK = TcK + 2097152;
    float* Qp  = ws + 6815744;          // overlays T region (dead after stage2)
    float* Kp  = Qp + 8388608;

    float* ctx      = (float*)d_out;
    float* attn_out = ctx + 2097152;

    // zero atomic destinations
    hipMemsetAsync(attn_out, 0, 131072 * sizeof(float), stream);
    hipMemsetAsync(TcQ, 0, 8388608 * sizeof(float), stream);   // all 4 T arrays
    hipMemsetAsync(FQ, 0, 4194304 * sizeof(float), stream);    // FQ + FK

    gen_mats<<<5120, 256, 0, stream>>>(CN, SN, CM, SM);

    // stage 1: K-split x2, z = input*2 + khalf
    stage1_fused<<<dim3(5, 64, 4), 256, 0, stream>>>(Q, K, CN, SN, TcQ, TsQ, TcK, TsK);

    // stage 2: K-split x4, z = split*8 + input*4 + batch
    stage2_fused<<<dim3(5, 16, 32), 256, 0, stream>>>(CM, SM, TcQ, TsQ, TcK, TsK, FQ, FK);

    // fill F columns 257..511 by conjugate symmetry
    mirror_f<<<8192, 256, 0, stream>>>(FQ, FK);

    // multi-scale conv gathers; SCALE folded into Qp
    conv_all<<<8192, 256, 0, stream>>>(FQ, Qp, wq[0], bq[0], wq[1], bq[1],
                                       wq[2], bq[2], wq[3], bq[3], SCALE);
    conv_all<<<8192, 256, 0, stream>>>(FK, Kp, wk[0], bk[0], wk[1], bk[1],
                                       wk[2], bk[2], wk[3], bk[3], 1.0f);

    // fused scores + softmax(p) + sum_q  -> attn_out
    scores_attn<<<dim3(16, 16, 32), 256, 0, stream>>>(Qp, Kp, attn_out);

    // context = colsum(V) broadcast over q
    context_kernel<<<32, 256, 0, stream>>>(V, ctx);
}